// Round 10
// baseline (410.555 us; speedup 1.0000x reference)
//
#include <hip/hip_runtime.h>
#include <math.h>

#define NB 46
#define NS 50
#define ND 768
#define GAMA 0.96875f
#define NM 2300   // NB*NS rows

using bfrag  = __attribute__((ext_vector_type(8))) short;   // 8 bf16 = 4 VGPRs
using f32x16 = __attribute__((ext_vector_type(16))) float;  // 32x32 acc

union FragU { unsigned u[4]; bfrag f; };

// ---------------- Kernel 1: QKV projections (+bias, +pe for Q,K) ----------
__global__ __launch_bounds__(256) void qkv_gemm(
    const float* __restrict__ text_emb, const float* __restrict__ emb,
    const float* __restrict__ Wq, const float* __restrict__ bq,
    const float* __restrict__ Wk, const float* __restrict__ bk,
    const float* __restrict__ Wv, const float* __restrict__ bv,
    float* __restrict__ Q, float* __restrict__ K, float* __restrict__ V)
{
    const int z = blockIdx.z;
    const float* X    = (z == 0) ? text_emb : emb;
    const float* W    = (z == 0) ? Wq : (z == 1) ? Wk : Wv;
    const float* bias = (z == 0) ? bq : (z == 1) ? bk : bv;
    float* out        = (z == 0) ? Q  : (z == 1) ? K  : V;

    __shared__ float Xs[16][68];
    __shared__ float Ws[16][68];

    const int tid = threadIdx.x;
    const int tx = tid & 15, ty = tid >> 4;
    const int m0 = blockIdx.x * 64, n0 = blockIdx.y * 64;

    const int lrow = tid >> 2;        // 0..63
    const int lk   = (tid & 3) * 4;   // 0,4,8,12

    float acc[4][4];
    #pragma unroll
    for (int i = 0; i < 4; i++)
        #pragma unroll
        for (int j = 0; j < 4; j++) acc[i][j] = 0.f;

    for (int k0 = 0; k0 < ND; k0 += 16) {
        float4 xv = make_float4(0.f, 0.f, 0.f, 0.f);
        const int xm = m0 + lrow;
        if (xm < NM) xv = *reinterpret_cast<const float4*>(&X[xm * ND + k0 + lk]);
        const float4 wv = *reinterpret_cast<const float4*>(&W[(n0 + lrow) * ND + k0 + lk]);
        Xs[lk + 0][lrow] = xv.x; Xs[lk + 1][lrow] = xv.y;
        Xs[lk + 2][lrow] = xv.z; Xs[lk + 3][lrow] = xv.w;
        Ws[lk + 0][lrow] = wv.x; Ws[lk + 1][lrow] = wv.y;
        Ws[lk + 2][lrow] = wv.z; Ws[lk + 3][lrow] = wv.w;
        __syncthreads();
        #pragma unroll
        for (int k = 0; k < 16; k++) {
            const float4 a  = *reinterpret_cast<const float4*>(&Xs[k][4 * ty]);
            const float4 b4 = *reinterpret_cast<const float4*>(&Ws[k][4 * tx]);
            const float av[4]  = {a.x,  a.y,  a.z,  a.w};
            const float bv4[4] = {b4.x, b4.y, b4.z, b4.w};
            #pragma unroll
            for (int i = 0; i < 4; i++)
                #pragma unroll
                for (int j = 0; j < 4; j++) acc[i][j] += av[i] * bv4[j];
        }
        __syncthreads();
    }

    const float C2 = -0.0239861701969175f; // -2*ln(10000)/768
    #pragma unroll
    for (int i = 0; i < 4; i++) {
        const int m = m0 + 4 * ty + i;
        if (m >= NM) continue;
        const int bpos = m / NS;  // pe indexed by BATCH position (faithful to source)
        #pragma unroll
        for (int j = 0; j < 4; j++) {
            const int n = n0 + 4 * tx + j;
            float v = acc[i][j] + bias[n];
            if (z < 2) {
                const int h = n >> 1;
                const float ang = (float)bpos * expf((float)h * C2);
                v += (n & 1) ? cosf(ang) : sinf(ang);
            }
            out[m * ND + n] = v;
        }
    }
}

// ---------------- Kernel 2: scores+softmax+ctx, and Ag = gamma*Q_trans -----
__global__ __launch_bounds__(64) void attn(
    const float* __restrict__ Q, const float* __restrict__ K,
    const float* __restrict__ V,
    const float* __restrict__ lin_w, const float* __restrict__ lin_b,
    float* __restrict__ Ag, float* __restrict__ ctx_out)
{
    const int bq = blockIdx.x;
    const int b = bq / NS, q = bq % NS;
    const int lane = threadIdx.x;

    const float* Qr = Q + (b * NS + q) * ND;
    float qv[12];
    #pragma unroll
    for (int m = 0; m < 12; m++) qv[m] = Qr[m * 64 + lane];

    // scores: lane k ends up holding score[k]*8
    float mysc = 0.f;
    for (int k = 0; k < NS; k++) {
        const float* Kr = K + (b * NS + k) * ND;
        float s = 0.f;
        #pragma unroll
        for (int m = 0; m < 12; m++) s += qv[m] * Kr[m * 64 + lane];
        #pragma unroll
        for (int off = 32; off; off >>= 1) s += __shfl_xor(s, off);
        if (lane == k) mysc = s * 8.f;
    }
    // Q_trans row q: lane j holds Qt[j]; write Ag = gamma*(Qt + lin_b)
    float myqt = 0.f;
    for (int j = 0; j < NS; j++) {
        const float* Lr = lin_w + j * ND;
        float s = 0.f;
        #pragma unroll
        for (int m = 0; m < 12; m++) s += qv[m] * Lr[m * 64 + lane];
        #pragma unroll
        for (int off = 32; off; off >>= 1) s += __shfl_xor(s, off);
        if (lane == j) myqt = s;
    }
    if (lane < NS)
        Ag[b * (NS * NS) + q * NS + lane] = GAMA * (myqt + lin_b[lane]);

    // softmax over lanes 0..49
    const float sc = (lane < NS) ? mysc : -INFINITY;
    float mx = sc;
    #pragma unroll
    for (int off = 32; off; off >>= 1) mx = fmaxf(mx, __shfl_xor(mx, off));
    const float e = (lane < NS) ? expf(sc - mx) : 0.f;
    float sum = e;
    #pragma unroll
    for (int off = 32; off; off >>= 1) sum += __shfl_xor(sum, off);
    const float p = e / sum;

    // ctx row = sum_k p_k * V[b,k,:]
    float acc[12];
    #pragma unroll
    for (int m = 0; m < 12; m++) acc[m] = 0.f;
    for (int k = 0; k < NS; k++) {
        const float pk = __shfl(p, k);
        const float* Vr = V + (b * NS + k) * ND;
        #pragma unroll
        for (int m = 0; m < 12; m++) acc[m] += pk * Vr[m * 64 + lane];
    }
    float* Cr = ctx_out + (b * NS + q) * ND;
    #pragma unroll
    for (int m = 0; m < 12; m++) Cr[m * 64 + lane] = acc[m];
}

// ---------------- Kernel 3: gamma-decay recurrence via MFMA ----------------
// rec[i,b,:,:] = Ag_b @ rec[i-1,b,:,:] + ctx[i], padded 50->64 on M,K.
// One wave per (b, 32-col chunk): 1104 blocks. A held in bf16 hi/lo MFMA
// fragments loaded ONCE from global. State packed (hi16|lo16) in LDS
// P[64][32] (bank = col, conflict-free), no barriers (DS in-order per wave).
// ctx for step i+1 prefetched before step i's stores (vmcnt FIFO, R6/R8).
// R9 lesson: NT stores ack only from HBM (~900+ cyc, 128B bursts); the
// vmcnt FIFO makes step i+2 wait on ALL of stores_i retiring -> recur ran at
// the NT-store drain rate (1.4 TB/s). Plain stores ack from L2 (~200 cyc,
// write-combined async writeback) -> store retirement leaves the critical
// path. rec is write-once; L2 pollution harmless (read set ~160 KB).
__device__ __forceinline__ void rec_step(
    int i, int b, int d0, int c, int h, bool pf,
    const bfrag (&Ah)[2][4], const bfrag (&Al)[2][4],
    float (&cur)[2][16], float (&nxt)[2][16],
    unsigned* P, const float* __restrict__ ctx, float* __restrict__ rec)
{
    // acc := ctx_i (pad rows already 0 in cur)
    f32x16 acc[2];
    #pragma unroll
    for (int mt = 0; mt < 2; mt++)
        #pragma unroll
        for (int g = 0; g < 16; g++)
            acc[mt][g] = cur[mt][g];

    // prefetch ctx_{i+1} BEFORE this step's stores (FIFO discipline)
    if (pf) {
        const float* __restrict__ ctxn = ctx + (size_t)(i + 1) * NS * ND + d0 + c;
        #pragma unroll
        for (int mt = 0; mt < 2; mt++)
            #pragma unroll
            for (int g = 0; g < 16; g++) {
                const int rg = 32 * mt + (g & 3) + 8 * (g >> 2) + 4 * h;
                nxt[mt][g] = (rg < NS) ? ctxn[(size_t)rg * ND] : 0.f;
            }
    }

    // B-frags of s_{i-1} from P
    bfrag Bh[4], Bl[4];
    #pragma unroll
    for (int kt = 0; kt < 4; kt++) {
        unsigned pw[8];
        #pragma unroll
        for (int j = 0; j < 8; j++)
            pw[j] = P[(16 * kt + 8 * h + j) * 32 + c];
        FragU uh, ul;
        #pragma unroll
        for (int t = 0; t < 4; t++) {
            uh.u[t] = (pw[2 * t] >> 16)     | (pw[2 * t + 1] & 0xFFFF0000u);
            ul.u[t] = (pw[2 * t] & 0xFFFFu) | (pw[2 * t + 1] << 16);
        }
        Bh[kt] = uh.f; Bl[kt] = ul.f;
    }

    // 12 MFMA per mt: hi*hi, hi*lo, lo*hi
    #pragma unroll
    for (int mt = 0; mt < 2; mt++) {
        f32x16 a = acc[mt];
        #pragma unroll
        for (int kt = 0; kt < 4; kt++)
            a = __builtin_amdgcn_mfma_f32_32x32x16_bf16(Ah[mt][kt], Bh[kt], a, 0, 0, 0);
        #pragma unroll
        for (int kt = 0; kt < 4; kt++)
            a = __builtin_amdgcn_mfma_f32_32x32x16_bf16(Ah[mt][kt], Bl[kt], a, 0, 0, 0);
        #pragma unroll
        for (int kt = 0; kt < 4; kt++)
            a = __builtin_amdgcn_mfma_f32_32x32x16_bf16(Al[mt][kt], Bh[kt], a, 0, 0, 0);
        acc[mt] = a;
    }

    // repack state into P (pad rows produce exact 0) + store rec (L2-acked)
    float* __restrict__ reci = rec + (size_t)(i * NB + b) * NS * ND + d0 + c;
    #pragma unroll
    for (int mt = 0; mt < 2; mt++)
        #pragma unroll
        for (int g = 0; g < 16; g++) {
            const int rg = 32 * mt + (g & 3) + 8 * (g >> 2) + 4 * h;
            const float v = acc[mt][g];
            const unsigned hi = __float_as_uint(v) & 0xFFFF0000u;
            const float res = v - __uint_as_float(hi);
            P[rg * 32 + c] = hi | (__float_as_uint(res) >> 16);
            if (rg < NS)
                reci[(size_t)rg * ND] = v;
        }
}

__global__ __launch_bounds__(64, 1) void recur(
    const float* __restrict__ Ag, const float* __restrict__ ctx,
    float* __restrict__ rec)
{
    const int blk   = blockIdx.x;          // 0..1103
    const int b     = blk / 24;
    const int chunk = blk - b * 24;        // 0..23 -> 32 cols
    const int l     = threadIdx.x;
    const int c     = l & 31;
    const int h     = l >> 5;
    const int d0    = chunk * 32;

    __shared__ unsigned P[64 * 32];        // packed state (hi16|lo16), 8 KB

    // ---- A fragments (hi/lo), ONCE, straight from global (L2-resident) ----
    const float* __restrict__ Ab = Ag + b * (NS * NS);
    bfrag Ah[2][4], Al[2][4];
    #pragma unroll
    for (int mt = 0; mt < 2; mt++) {
        const int row = 32 * mt + c;
        const bool rok = row < NS;
        const float* __restrict__ Arow = Ab + row * NS;
        #pragma unroll
        for (int kt = 0; kt < 4; kt++) {
            FragU uh, ul;
            #pragma unroll
            for (int t = 0; t < 4; t++) {
                const int k0 = 16 * kt + 8 * h + 2 * t;
                const float e = (rok && k0     < NS) ? Arow[k0]     : 0.f;
                const float o = (rok && k0 + 1 < NS) ? Arow[k0 + 1] : 0.f;
                const unsigned ue = __float_as_uint(e), uo = __float_as_uint(o);
                uh.u[t] = (ue >> 16) | (uo & 0xFFFF0000u);
                const float re = e - __uint_as_float(ue & 0xFFFF0000u);
                const float ro = o - __uint_as_float(uo & 0xFFFF0000u);
                ul.u[t] = (__float_as_uint(re) >> 16) | (__float_as_uint(ro) & 0xFFFF0000u);
            }
            Ah[mt][kt] = uh.f; Al[mt][kt] = ul.f;
        }
    }

    // ---- step 0: cvA = ctx[0]; prefetch ctx[1] -> cvB; then pack/store ----
    float cvA[2][16], cvB[2][16];
    {
        const float* __restrict__ c0 = ctx + d0 + c;
        #pragma unroll
        for (int mt = 0; mt < 2; mt++)
            #pragma unroll
            for (int g = 0; g < 16; g++) {
                const int rg = 32 * mt + (g & 3) + 8 * (g >> 2) + 4 * h;
                cvA[mt][g] = (rg < NS) ? c0[(size_t)rg * ND] : 0.f;
            }
        const float* __restrict__ c1 = ctx + NS * ND + d0 + c;
        #pragma unroll
        for (int mt = 0; mt < 2; mt++)
            #pragma unroll
            for (int g = 0; g < 16; g++) {
                const int rg = 32 * mt + (g & 3) + 8 * (g >> 2) + 4 * h;
                cvB[mt][g] = (rg < NS) ? c1[(size_t)rg * ND] : 0.f;
            }
        float* __restrict__ r0 = rec + (size_t)b * NS * ND + d0 + c;
        #pragma unroll
        for (int mt = 0; mt < 2; mt++)
            #pragma unroll
            for (int g = 0; g < 16; g++) {
                const int rg = 32 * mt + (g & 3) + 8 * (g >> 2) + 4 * h;
                const float v = cvA[mt][g];
                const unsigned hi = __float_as_uint(v) & 0xFFFF0000u;
                const float res = v - __uint_as_float(hi);
                P[rg * 32 + c] = hi | (__float_as_uint(res) >> 16);
                if (rg < NS)
                    r0[(size_t)rg * ND] = v;
            }
    }

    // ---- steps 1..45, 2x unrolled ping-pong (static indices, rule #20) ----
    for (int i = 1; i < NB; i += 2) {
        rec_step(i, b, d0, c, h, (i + 1 < NB), Ah, Al, cvB, cvA, P, ctx, rec);
        if (i + 1 < NB)
            rec_step(i + 1, b, d0, c, h, (i + 2 < NB), Ah, Al, cvA, cvB, P, ctx, rec);
    }
}

extern "C" void kernel_launch(void* const* d_in, const int* in_sizes, int n_in,
                              void* d_out, int out_size, void* d_ws, size_t ws_size,
                              hipStream_t stream) {
    const float* text_emb = (const float*)d_in[0];
    const float* emb      = (const float*)d_in[1];
    const float* Wq = (const float*)d_in[2]; const float* bq = (const float*)d_in[3];
    const float* Wk = (const float*)d_in[4]; const float* bk = (const float*)d_in[5];
    const float* Wv = (const float*)d_in[6]; const float* bv = (const float*)d_in[7];
    const float* lw = (const float*)d_in[8]; const float* lb = (const float*)d_in[9];

    float* out = (float*)d_out;
    float* ctx = out;                          // [46,50,768]
    float* rec = out + NB * NS * ND;           // [46,46,50,768]

    float* ws = (float*)d_ws;                  // needs 21.7 MB
    float* Q  = ws;
    float* K  = Q + NB * NS * ND;
    float* V  = K + NB * NS * ND;
    float* Ag = V + NB * NS * ND;              // gamma * Q_trans, [46,50,50]

    qkv_gemm<<<dim3(36, 12, 3), 256, 0, stream>>>(text_emb, emb, Wq, bq, Wk, bk, Wv, bv, Q, K, V);
    attn<<<dim3(NM), 64, 0, stream>>>(Q, K, V, lw, lb, Ag, ctx);
    recur<<<dim3(1104), 64, 0, stream>>>(Ag, ctx, rec);
}